// Round 4
// baseline (205.637 us; speedup 1.0000x reference)
//
#include <hip/hip_runtime.h>

#define NP 250000   // P: permutations
#define NN 100000   // N: nodes
#define NE 400000   // E: edges
#define LL 16
#define DD 16
#define MM (NP * LL)        // 4,000,000
#define NTILES (NP / 16)    // 15625 exact
#define PERM_BLOCKS 512
#define GWAVES (PERM_BLOCKS * 4)   // 2048 waves, ~7.6 tiles each

typedef __bf16 bf16x8 __attribute__((ext_vector_type(8)));
typedef float  f32x4  __attribute__((ext_vector_type(4)));
typedef int    i32x4  __attribute__((ext_vector_type(4)));

__device__ __forceinline__ float4 fma4(float a, float4 b, float4 c) {
    float4 r;
    r.x = fmaf(a, b.x, c.x);
    r.y = fmaf(a, b.y, c.y);
    r.z = fmaf(a, b.z, c.z);
    r.w = fmaf(a, b.w, c.w);
    return r;
}

// K-mapping for mfma_16x16x32_bf16, kb (0..7), lane (quad=lane>>4, c=lane&15):
//   d = 8*(quad&1) + j,  l = 8*(quad>>1) + kb
// wfrag[kb*512 + lane*8 + j] = weights[d][c][l]  (B-fragment order)
__global__ __launch_bounds__(256) void init_kernel(
    const float* __restrict__ w,          // [16,16,16] (d,c,l)
    const float* __restrict__ nfeat,      // [N,16]
    const float* __restrict__ bond_emb,   // [4,16]
    const int* __restrict__ e_col,        // [M]
    const int* __restrict__ efeat_idx,    // [E]
    const float* __restrict__ degs,       // [N]
    const float* __restrict__ W0,         // [1,32]
    const float* __restrict__ b0,         // [32]
    const float* __restrict__ W1,         // [32,16]
    const float* __restrict__ b1,         // [16]
    __bf16* __restrict__ wfrag,           // [8*64*8]
    __bf16* __restrict__ nfeat_bf,        // [N,16]
    __bf16* __restrict__ bond_bf,         // [4,16]
    unsigned char* __restrict__ be2,      // [M/4]
    float* __restrict__ fd,               // [N,16] or nullptr
    float* __restrict__ out)              // [N,16] -> zeroed
{
    int t = blockIdx.x * 256 + threadIdx.x;
    if (t < 4096) {
        int kb = t >> 9;
        int lane = (t >> 3) & 63;
        int j = t & 7;
        int quad = lane >> 4, c = lane & 15;
        int d = ((quad & 1) << 3) + j;
        int l = ((quad >> 1) << 3) + kb;
        wfrag[t] = (__bf16)w[d * 256 + c * 16 + l];
    }
    if (t < NN * DD) {
        nfeat_bf[t] = (__bf16)nfeat[t];
        out[t] = 0.f;
    }
    if (t < 64) bond_bf[t] = (__bf16)bond_emb[t];
    if (t < MM / 4) {
        int4 ec = *(const int4*)(e_col + t * 4);
        unsigned int c0 = (unsigned int)efeat_idx[ec.x] & 3u;
        unsigned int c1 = (unsigned int)efeat_idx[ec.y] & 3u;
        unsigned int c2 = (unsigned int)efeat_idx[ec.z] & 3u;
        unsigned int c3 = (unsigned int)efeat_idx[ec.w] & 3u;
        be2[t] = (unsigned char)(c0 | (c1 << 2) | (c2 << 4) | (c3 << 6));
    }
    if (fd != nullptr && t < NN) {
        float dg = degs[t];
        float4 a0 = ((const float4*)b1)[0];
        float4 a1 = ((const float4*)b1)[1];
        float4 a2 = ((const float4*)b1)[2];
        float4 a3 = ((const float4*)b1)[3];
#pragma unroll
        for (int j2 = 0; j2 < 32; ++j2) {
            float h = fmaxf(fmaf(dg, W0[j2], b0[j2]), 0.f);
            const float4* w1r = (const float4*)(W1 + j2 * 16);
            a0 = fma4(h, w1r[0], a0);
            a1 = fma4(h, w1r[1], a1);
            a2 = fma4(h, w1r[2], a2);
            a3 = fma4(h, w1r[3], a3);
        }
        float4* o = (float4*)(fd + (size_t)t * DD);
        o[0] = a0; o[1] = a1; o[2] = a2; o[3] = a3;
    }
}

// ---- pipelined perm kernel -------------------------------------------------
// 2048 waves, ~7.6 tiles each. Depth-2 GATHER pipeline (the round-4 change):
// at any moment TWO tiles' nfr gathers (16 requests/wave) are in flight, and
// the gather issue->use lead is a full step (~1.3 compute phases) instead of
// half a step. Early streams run 3 tiles ahead, late streams (+fd gather,
// prs/pv/gv for the epilogue) 2 ahead. All prefetch loads are issued BEFORE
// the epilogue atomics so gather waits never queue behind atomic acks in the
// in-order vmcnt queue. Named ping-pong slots only (no scratch).

struct Early { i32x4 nca, ncb, pr; };
struct Gath  { bf16x8 nfr[8]; };
struct Late  { f32x4 nva, nvb, eva, evb, pv, gv; i32x4 prs; unsigned int be16; };

__device__ __forceinline__ void load_early(Early& e, int tile, int col, int lhalf, int quad,
        const int* __restrict__ n_col, const int* __restrict__ p_row) {
    const int pbase = tile * 16;
    const int mbase = (pbase + col) * LL + lhalf * 8;
    e.nca = __builtin_nontemporal_load((const i32x4*)(n_col + mbase));
    e.ncb = __builtin_nontemporal_load((const i32x4*)(n_col + mbase + 4));
    e.pr  = __builtin_nontemporal_load((const i32x4*)(p_row + pbase + quad * 4));
}

__device__ __forceinline__ void load_late(Late& lt, int tile, int col, int lhalf, int quad,
        const float* __restrict__ n_val, const float* __restrict__ e_val,
        const unsigned char* __restrict__ be2, const float* __restrict__ p_val,
        const Early& e, const float* __restrict__ fd) {
    const int pbase = tile * 16;
    const int mbase = (pbase + col) * LL + lhalf * 8;
    lt.nva = __builtin_nontemporal_load((const f32x4*)(n_val + mbase));
    lt.nvb = __builtin_nontemporal_load((const f32x4*)(n_val + mbase + 4));
    lt.eva = __builtin_nontemporal_load((const f32x4*)(e_val + mbase));
    lt.evb = __builtin_nontemporal_load((const f32x4*)(e_val + mbase + 4));
    lt.pv  = __builtin_nontemporal_load((const f32x4*)(p_val + pbase + quad * 4));
    lt.be16 = (unsigned int)__builtin_nontemporal_load(
                  (const unsigned short*)(be2 + (mbase >> 2)));
    lt.prs = e.pr;
#pragma unroll
    for (int r = 0; r < 4; ++r)
        lt.gv[r] = fd ? fd[(size_t)e.pr[r] * DD + col] : 1.f;
}

__device__ __forceinline__ void issue_gathers(Gath& g, const Early& e,
        const __bf16* __restrict__ nfeat_bf, int half) {
    int ncs[8] = {e.nca[0], e.nca[1], e.nca[2], e.nca[3],
                  e.ncb[0], e.ncb[1], e.ncb[2], e.ncb[3]};
#pragma unroll
    for (int kb = 0; kb < 8; ++kb)
        g.nfr[kb] = *(const bf16x8*)(nfeat_bf + (size_t)ncs[kb] * DD + half * 8);
}

#define KSTEP(G, KB, NV, EV, J) do { \
    unsigned int b = (be >> (2 * (KB))) & 3u; \
    bf16x8 blo = (b & 1) ? bq1 : bq0; \
    bf16x8 bhi = (b & 1) ? bq3 : bq2; \
    bf16x8 bsel = (b & 2) ? bhi : blo; \
    float nv = (NV)[J], ev = (EV)[J]; \
    bf16x8 af; \
    _Pragma("unroll") \
    for (int j = 0; j < 8; ++j) \
        af[j] = (__bf16)fmaf(nv, (float)G.nfr[KB][j], ev * (float)bsel[j]); \
    acc = __builtin_amdgcn_mfma_f32_16x16x32_bf16(af, wf[KB], acc, 0, 0, 0); \
} while (0)

// Computes tile tc from slot C. Prefetch: early(tc+3G) into slot N,
// gathers+late(tc+2G) into slot C (freed by the KSTEPs / snapshot).
#define STEP(C, N) { \
    f32x4 acc = {0.f, 0.f, 0.f, 0.f}; \
    const unsigned int be = lat##C.be16; \
    KSTEP(g##C, 0, lat##C.nva, lat##C.eva, 0); \
    KSTEP(g##C, 1, lat##C.nva, lat##C.eva, 1); \
    KSTEP(g##C, 2, lat##C.nva, lat##C.eva, 2); \
    KSTEP(g##C, 3, lat##C.nva, lat##C.eva, 3); \
    { int te = tc + 3 * GWAVES; \
      if (te < NTILES) load_early(ear##N, te, col, lhalf, quad, n_col, p_row); } \
    KSTEP(g##C, 4, lat##C.nvb, lat##C.evb, 0); \
    KSTEP(g##C, 5, lat##C.nvb, lat##C.evb, 1); \
    KSTEP(g##C, 6, lat##C.nvb, lat##C.evb, 2); \
    KSTEP(g##C, 7, lat##C.nvb, lat##C.evb, 3); \
    f32x4 pvl = lat##C.pv, gvl = lat##C.gv; \
    i32x4 prl = lat##C.prs; \
    { int tg = tc + 2 * GWAVES; \
      if (tg < NTILES) { \
          issue_gathers(g##C, ear##C, nfeat_bf, half); \
          load_late(lat##C, tg, col, lhalf, quad, n_val, e_val, be2, p_val, ear##C, fd); \
      } } \
    _Pragma("unroll") \
    for (int r = 0; r < 4; ++r) { \
        float v = fmaxf(acc[r] + bias_c, 0.f) * pvl[r] * gvl[r]; \
        unsafeAtomicAdd(out + (size_t)prl[r] * DD + col, v); \
    } \
    tc += GWAVES; \
    if (tc >= NTILES) goto tail_done; \
}

__global__ __launch_bounds__(256) void perm_kernel(
    const __bf16* __restrict__ nfeat_bf,   // [N,16] bf16
    const int* __restrict__ n_col,         // [M]
    const float* __restrict__ n_val,       // [M]
    const float* __restrict__ e_val,       // [M]
    const unsigned char* __restrict__ be2, // [M/4] packed bond indices
    const int* __restrict__ p_row,         // [P]
    const float* __restrict__ p_val,       // [P]
    const __bf16* __restrict__ wfrag,      // [8*64*8]
    const float* __restrict__ bias,        // [16]
    const __bf16* __restrict__ bond_bf,    // [4,16] bf16
    const float* __restrict__ fd,          // [N,16] gate table, or nullptr
    float* __restrict__ out)               // [N,16] zero-initialized
{
    const int wid  = threadIdx.x >> 6;
    const int lane = threadIdx.x & 63;
    const int gw   = blockIdx.x * 4 + wid;   // 0..GWAVES-1
    const int quad = lane >> 4;
    const int col  = lane & 15;
    const int half = quad & 1;
    const int lhalf = quad >> 1;

    // constants, L2-hot (8 KB shared by all waves)
    bf16x8 wf[8];
#pragma unroll
    for (int kb = 0; kb < 8; ++kb)
        wf[kb] = *(const bf16x8*)(wfrag + (kb * 64 + lane) * 8);
    const bf16x8 bq0 = *(const bf16x8*)(bond_bf + 0 * 16 + half * 8);
    const bf16x8 bq1 = *(const bf16x8*)(bond_bf + 1 * 16 + half * 8);
    const bf16x8 bq2 = *(const bf16x8*)(bond_bf + 2 * 16 + half * 8);
    const bf16x8 bq3 = *(const bf16x8*)(bond_bf + 3 * 16 + half * 8);
    const float bias_c = bias[col];

    Early earA, earB;
    Gath  gA, gB;
    Late  latA, latB;

    int tc = gw;

    // prologue — unguarded: gw + 2*GWAVES <= 2047 + 4096 < NTILES always.
    load_early(earA, tc, col, lhalf, quad, n_col, p_row);
    load_early(earB, tc + GWAVES, col, lhalf, quad, n_col, p_row);
    issue_gathers(gA, earA, nfeat_bf, half);
    load_late(latA, tc, col, lhalf, quad, n_val, e_val, be2, p_val, earA, fd);
    load_early(earA, tc + 2 * GWAVES, col, lhalf, quad, n_col, p_row); // slot A reuse
    issue_gathers(gB, earB, nfeat_bf, half);
    load_late(latB, tc + GWAVES, col, lhalf, quad, n_val, e_val, be2, p_val, earB, fd);

    for (;;) {
        STEP(A, B);
        STEP(B, A);
    }
tail_done: ;
}

// fallback only (workspace too small for fd table)
__global__ __launch_bounds__(256) void gate_kernel(
    const float* __restrict__ degs,  // [N]
    const float* __restrict__ W0,    // [1,32]
    const float* __restrict__ b0,    // [32]
    const float* __restrict__ W1,    // [32,16]
    const float* __restrict__ b1,    // [16]
    float* __restrict__ out)         // [N,16] in-place multiply
{
    int n = blockIdx.x * 256 + threadIdx.x;
    if (n >= NN) return;
    float dg = degs[n];
    float4 a0 = ((const float4*)b1)[0];
    float4 a1 = ((const float4*)b1)[1];
    float4 a2 = ((const float4*)b1)[2];
    float4 a3 = ((const float4*)b1)[3];
#pragma unroll
    for (int j = 0; j < 32; ++j) {
        float h = fmaxf(fmaf(dg, W0[j], b0[j]), 0.f);
        const float4* w1r = (const float4*)(W1 + j * 16);
        a0 = fma4(h, w1r[0], a0);
        a1 = fma4(h, w1r[1], a1);
        a2 = fma4(h, w1r[2], a2);
        a3 = fma4(h, w1r[3], a3);
    }
    float4* o = (float4*)(out + (size_t)n * DD);
    float4 v0 = o[0], v1 = o[1], v2 = o[2], v3 = o[3];
    v0.x *= a0.x; v0.y *= a0.y; v0.z *= a0.z; v0.w *= a0.w;
    v1.x *= a1.x; v1.y *= a1.y; v1.z *= a1.z; v1.w *= a1.w;
    v2.x *= a2.x; v2.y *= a2.y; v2.z *= a2.z; v2.w *= a2.w;
    v3.x *= a3.x; v3.y *= a3.y; v3.z *= a3.z; v3.w *= a3.w;
    o[0] = v0; o[1] = v1; o[2] = v2; o[3] = v3;
}

extern "C" void kernel_launch(void* const* d_in, const int* in_sizes, int n_in,
                              void* d_out, int out_size, void* d_ws, size_t ws_size,
                              hipStream_t stream) {
    const float* nfeat     = (const float*)d_in[0];
    const int*   efeat_idx = (const int*)d_in[1];
    // d_in[2] n_row = arange(M), unused
    const int*   n_col     = (const int*)d_in[3];
    const float* n_val     = (const float*)d_in[4];
    // d_in[5] e_row = arange(M), unused
    const int*   e_col     = (const int*)d_in[6];
    const float* e_val     = (const float*)d_in[7];
    const int*   p_row     = (const int*)d_in[8];
    // d_in[9] p_col = arange(P), unused
    const float* p_val     = (const float*)d_in[10];
    const float* degs      = (const float*)d_in[11];
    const float* weights   = (const float*)d_in[12];
    const float* bias      = (const float*)d_in[13];
    const float* W0        = (const float*)d_in[14];
    const float* b0        = (const float*)d_in[15];
    const float* W1        = (const float*)d_in[16];
    const float* b1        = (const float*)d_in[17];
    const float* bond_emb  = (const float*)d_in[18];

    float* out = (float*)d_out;

    // ws layout (16B-aligned blocks):
    //   wfrag 8KB | nfeat_bf 3.2MB | bond 128B | be2 1MB | fd 6.4MB (if it fits)
    char* wsb = (char*)d_ws;
    __bf16*        wfrag    = (__bf16*)wsb;                                // 8192 B
    __bf16*        nfeat_bf = (__bf16*)(wsb + 8192);                       // 3,200,000 B
    __bf16*        bond_bf  = (__bf16*)(wsb + 8192 + 3200000);             // 128 B
    unsigned char* be2      = (unsigned char*)(wsb + 8192 + 3200000 + 128);// 1,000,000 B
    const size_t base_need  = 8192 + 3200000 + 128 + 1000000;              // 4,208,320
    const bool   fuse_gate  = ws_size >= base_need + (size_t)NN * DD * 4;
    float*         fd       = fuse_gate ? (float*)(wsb + base_need) : nullptr;

    // grid must cover max(NN*DD, MM/4) = 1.6M threads
    init_kernel<<<(NN * DD + 255) / 256, 256, 0, stream>>>(
        weights, nfeat, bond_emb, e_col, efeat_idx,
        degs, W0, b0, W1, b1,
        wfrag, nfeat_bf, bond_bf, be2, fd, out);

    // 2048 waves (r2 config restored), depth-2 gather pipeline
    perm_kernel<<<PERM_BLOCKS, 256, 0, stream>>>(
        nfeat_bf, n_col, n_val, e_val, be2, p_row, p_val,
        wfrag, bias, bond_bf, fd, out);

    if (!fuse_gate)
        gate_kernel<<<(NN + 255) / 256, 256, 0, stream>>>(degs, W0, b0, W1, b1, out);
}

// Round 5
// 203.975 us; speedup vs baseline: 1.0081x; 1.0081x over previous
//
#include <hip/hip_runtime.h>

#define NP 250000   // P: permutations
#define NN 100000   // N: nodes
#define NE 400000   // E: edges
#define LL 16
#define DD 16
#define MM (NP * LL)        // 4,000,000
#define NTILES (NP / 16)    // 15625 exact
#define PERM_BLOCKS 512
#define GWAVES (PERM_BLOCKS * 4)   // 2048 waves, ~7.6 tiles each

typedef __bf16 bf16x8 __attribute__((ext_vector_type(8)));
typedef float  f32x4  __attribute__((ext_vector_type(4)));
typedef int    i32x4  __attribute__((ext_vector_type(4)));

__device__ __forceinline__ float4 fma4(float a, float4 b, float4 c) {
    float4 r;
    r.x = fmaf(a, b.x, c.x);
    r.y = fmaf(a, b.y, c.y);
    r.z = fmaf(a, b.z, c.z);
    r.w = fmaf(a, b.w, c.w);
    return r;
}

// K-mapping for mfma_16x16x32_bf16, kb (0..7), lane (quad=lane>>4, c=lane&15):
//   d = 8*(quad&1) + j,  l = 8*(quad>>1) + kb
// wfrag[kb*512 + lane*8 + j] = weights[d][c][l]  (B-fragment order)
// ei2: 2-bit packed efeat_idx (E/4 = 100,000 bytes) — the be2 gather moves
// to be2_kernel's LDS. Fallback (ei2==nullptr): old 4M-gather be2 path.
__global__ __launch_bounds__(256) void init_kernel(
    const float* __restrict__ w,          // [16,16,16] (d,c,l)
    const float* __restrict__ nfeat,      // [N,16]
    const float* __restrict__ bond_emb,   // [4,16]
    const int* __restrict__ e_col,        // [M]
    const int* __restrict__ efeat_idx,    // [E]
    const float* __restrict__ degs,       // [N]
    const float* __restrict__ W0,         // [1,32]
    const float* __restrict__ b0,         // [32]
    const float* __restrict__ W1,         // [32,16]
    const float* __restrict__ b1,         // [16]
    __bf16* __restrict__ wfrag,           // [8*64*8]
    __bf16* __restrict__ nfeat_bf,        // [N,16]
    __bf16* __restrict__ bond_bf,         // [4,16]
    unsigned char* __restrict__ be2,      // [M/4] (fallback path only)
    unsigned int* __restrict__ ei2,       // [E/16] packed, or nullptr
    float* __restrict__ fd,               // [N,16] or nullptr
    float* __restrict__ out)              // [N,16] -> zeroed
{
    int t = blockIdx.x * 256 + threadIdx.x;
    if (t < 4096) {
        int kb = t >> 9;
        int lane = (t >> 3) & 63;
        int j = t & 7;
        int quad = lane >> 4, c = lane & 15;
        int d = ((quad & 1) << 3) + j;
        int l = ((quad >> 1) << 3) + kb;
        wfrag[t] = (__bf16)w[d * 256 + c * 16 + l];
    }
    if (t < NN * DD) {
        nfeat_bf[t] = (__bf16)nfeat[t];
        out[t] = 0.f;
    }
    if (t < 64) bond_bf[t] = (__bf16)bond_emb[t];
    if (ei2 != nullptr) {
        // pack efeat_idx -> 2 bits/edge: uint t covers edges t*16..t*16+15
        if (t < NE / 16) {
            const int4* src = (const int4*)(efeat_idx + t * 16);
            int4 a = src[0], b = src[1], c4 = src[2], d4 = src[3];
            unsigned int u = 0;
            u |= ((unsigned)a.x & 3u) << 0;  u |= ((unsigned)a.y & 3u) << 2;
            u |= ((unsigned)a.z & 3u) << 4;  u |= ((unsigned)a.w & 3u) << 6;
            u |= ((unsigned)b.x & 3u) << 8;  u |= ((unsigned)b.y & 3u) << 10;
            u |= ((unsigned)b.z & 3u) << 12; u |= ((unsigned)b.w & 3u) << 14;
            u |= ((unsigned)c4.x & 3u) << 16; u |= ((unsigned)c4.y & 3u) << 18;
            u |= ((unsigned)c4.z & 3u) << 20; u |= ((unsigned)c4.w & 3u) << 22;
            u |= ((unsigned)d4.x & 3u) << 24; u |= ((unsigned)d4.y & 3u) << 26;
            u |= ((unsigned)d4.z & 3u) << 28; u |= ((unsigned)d4.w & 3u) << 30;
            ei2[t] = u;
        }
    } else {
        // fallback: direct 4M-gather be2 build (the old slow path)
        if (t < MM / 4) {
            int4 ec = *(const int4*)(e_col + t * 4);
            unsigned int c0 = (unsigned int)efeat_idx[ec.x] & 3u;
            unsigned int c1 = (unsigned int)efeat_idx[ec.y] & 3u;
            unsigned int c2 = (unsigned int)efeat_idx[ec.z] & 3u;
            unsigned int c3 = (unsigned int)efeat_idx[ec.w] & 3u;
            be2[t] = (unsigned char)(c0 | (c1 << 2) | (c2 << 4) | (c3 << 6));
        }
    }
    if (fd != nullptr && t < NN) {
        float dg = degs[t];
        float4 a0 = ((const float4*)b1)[0];
        float4 a1 = ((const float4*)b1)[1];
        float4 a2 = ((const float4*)b1)[2];
        float4 a3 = ((const float4*)b1)[3];
#pragma unroll
        for (int j2 = 0; j2 < 32; ++j2) {
            float h = fmaxf(fmaf(dg, W0[j2], b0[j2]), 0.f);
            const float4* w1r = (const float4*)(W1 + j2 * 16);
            a0 = fma4(h, w1r[0], a0);
            a1 = fma4(h, w1r[1], a1);
            a2 = fma4(h, w1r[2], a2);
            a3 = fma4(h, w1r[3], a3);
        }
        float4* o = (float4*)(fd + (size_t)t * DD);
        o[0] = a0; o[1] = a1; o[2] = a2; o[3] = a3;
    }
}

// be2 via LDS: each block stages the full 100 KB packed table (L2-hot after
// block 0), then the 4M random efeat lookups become LDS byte-reads instead of
// L2-gather line-touches (the wall init was paying). e_col is read as a
// coalesced stream. 250 blocks x 4000 be2-bytes each.
__global__ __launch_bounds__(256) void be2_kernel(
    const int* __restrict__ e_col,             // [M]
    const unsigned int* __restrict__ ei2,      // [E/16]
    unsigned char* __restrict__ be2)           // [M/4]
{
    __shared__ unsigned char lds[NE / 4];      // 100,000 B (1 block/CU)
    const int tid = threadIdx.x;
    // stage: 6250 uint4 = 100,000 B
    for (int i = tid; i < NE / 64; i += 256)
        ((uint4*)lds)[i] = ((const uint4*)ei2)[i];
    __syncthreads();

    const int base = blockIdx.x * 4000;        // 250 * 4000 = 1,000,000 exact
#pragma unroll
    for (int r = 0; r < 16; ++r) {
        int off = r * 256 + tid;
        if (off < 4000) {
            int bi = base + off;
            int4 ec = ((const int4*)e_col)[bi];   // e_col[4*bi .. 4*bi+3], coalesced
            unsigned int v0 = lds[ec.x >> 2], s0 = ((unsigned)ec.x & 3u) * 2u;
            unsigned int v1 = lds[ec.y >> 2], s1 = ((unsigned)ec.y & 3u) * 2u;
            unsigned int v2 = lds[ec.z >> 2], s2 = ((unsigned)ec.z & 3u) * 2u;
            unsigned int v3 = lds[ec.w >> 2], s3 = ((unsigned)ec.w & 3u) * 2u;
            unsigned int b = ((v0 >> s0) & 3u) | (((v1 >> s1) & 3u) << 2)
                           | (((v2 >> s2) & 3u) << 4) | (((v3 >> s3) & 3u) << 6);
            be2[bi] = (unsigned char)b;
        }
    }
}

// ---- pipelined perm kernel (exact round-2 structure, best measured) --------
// 2048 waves, ~7.6 tiles each. Depth-3 pipeline:
//   streams(t+2) in flight (HBM) / gathers(t+1) in flight (L2) / compute(t).

struct Early { i32x4 nca, ncb, pr; };
struct Late  { f32x4 nva, nvb, eva, evb, pv; unsigned int be16; };
struct Gath  { bf16x8 nfr[8]; float gv[4]; int prs[4]; };

__device__ __forceinline__ void load_early(Early& e, int tile, int col, int lhalf, int quad,
        const int* __restrict__ n_col, const int* __restrict__ p_row) {
    const int pbase = tile * 16;
    const int mbase = (pbase + col) * LL + lhalf * 8;
    e.nca = __builtin_nontemporal_load((const i32x4*)(n_col + mbase));
    e.ncb = __builtin_nontemporal_load((const i32x4*)(n_col + mbase + 4));
    e.pr  = __builtin_nontemporal_load((const i32x4*)(p_row + pbase + quad * 4));
}

__device__ __forceinline__ void load_late(Late& lt, int tile, int col, int lhalf, int quad,
        const float* __restrict__ n_val, const float* __restrict__ e_val,
        const unsigned char* __restrict__ be2, const float* __restrict__ p_val) {
    const int pbase = tile * 16;
    const int mbase = (pbase + col) * LL + lhalf * 8;
    lt.nva = __builtin_nontemporal_load((const f32x4*)(n_val + mbase));
    lt.nvb = __builtin_nontemporal_load((const f32x4*)(n_val + mbase + 4));
    lt.eva = __builtin_nontemporal_load((const f32x4*)(e_val + mbase));
    lt.evb = __builtin_nontemporal_load((const f32x4*)(e_val + mbase + 4));
    lt.pv  = __builtin_nontemporal_load((const f32x4*)(p_val + pbase + quad * 4));
    lt.be16 = (unsigned int)__builtin_nontemporal_load(
                  (const unsigned short*)(be2 + (mbase >> 2)));
}

__device__ __forceinline__ void issue_gathers(Gath& g, const Early& e,
        const __bf16* __restrict__ nfeat_bf, const float* __restrict__ fd,
        int half, int col) {
    int ncs[8] = {e.nca[0], e.nca[1], e.nca[2], e.nca[3],
                  e.ncb[0], e.ncb[1], e.ncb[2], e.ncb[3]};
#pragma unroll
    for (int kb = 0; kb < 8; ++kb)
        g.nfr[kb] = *(const bf16x8*)(nfeat_bf + (size_t)ncs[kb] * DD + half * 8);
#pragma unroll
    for (int r = 0; r < 4; ++r) {
        g.prs[r] = e.pr[r];
        g.gv[r] = fd ? fd[(size_t)e.pr[r] * DD + col] : 1.f;
    }
}

#define KSTEP(G, KB, NV, EV, J) do { \
    unsigned int b = (be >> (2 * (KB))) & 3u; \
    bf16x8 blo = (b & 1) ? bq1 : bq0; \
    bf16x8 bhi = (b & 1) ? bq3 : bq2; \
    bf16x8 bsel = (b & 2) ? bhi : blo; \
    float nv = (NV)[J], ev = (EV)[J]; \
    bf16x8 af; \
    _Pragma("unroll") \
    for (int j = 0; j < 8; ++j) \
        af[j] = (__bf16)fmaf(nv, (float)G.nfr[KB][j], ev * (float)bsel[j]); \
    acc = __builtin_amdgcn_mfma_f32_16x16x32_bf16(af, wf[KB], acc, 0, 0, 0); \
} while (0)

#define STEP(C, N) { \
    f32x4 acc = {0.f, 0.f, 0.f, 0.f}; \
    const unsigned int be = lat##C.be16; \
    KSTEP(g##C, 0, lat##C.nva, lat##C.eva, 0); \
    KSTEP(g##C, 1, lat##C.nva, lat##C.eva, 1); \
    KSTEP(g##C, 2, lat##C.nva, lat##C.eva, 2); \
    KSTEP(g##C, 3, lat##C.nva, lat##C.eva, 3); \
    if (tn < NTILES) issue_gathers(g##N, ear##N, nfeat_bf, fd, half, col); \
    if (tf < NTILES) load_early(ear##C, tf, col, lhalf, quad, n_col, p_row); \
    KSTEP(g##C, 4, lat##C.nvb, lat##C.evb, 0); \
    KSTEP(g##C, 5, lat##C.nvb, lat##C.evb, 1); \
    KSTEP(g##C, 6, lat##C.nvb, lat##C.evb, 2); \
    KSTEP(g##C, 7, lat##C.nvb, lat##C.evb, 3); \
    _Pragma("unroll") \
    for (int r = 0; r < 4; ++r) { \
        float v = fmaxf(acc[r] + bias_c, 0.f) * lat##C.pv[r] * g##C.gv[r]; \
        unsafeAtomicAdd(out + (size_t)g##C.prs[r] * DD + col, v); \
    } \
    if (tf < NTILES) load_late(lat##C, tf, col, lhalf, quad, n_val, e_val, be2, p_val); \
    if (tn >= NTILES) goto tail_done; \
    tn = tf; tf += GWAVES; \
}

__global__ __launch_bounds__(256) void perm_kernel(
    const __bf16* __restrict__ nfeat_bf,   // [N,16] bf16
    const int* __restrict__ n_col,         // [M]
    const float* __restrict__ n_val,       // [M]
    const float* __restrict__ e_val,       // [M]
    const unsigned char* __restrict__ be2, // [M/4] packed bond indices
    const int* __restrict__ p_row,         // [P]
    const float* __restrict__ p_val,       // [P]
    const __bf16* __restrict__ wfrag,      // [8*64*8]
    const float* __restrict__ bias,        // [16]
    const __bf16* __restrict__ bond_bf,    // [4,16] bf16
    const float* __restrict__ fd,          // [N,16] gate table, or nullptr
    float* __restrict__ out)               // [N,16] zero-initialized
{
    const int wid  = threadIdx.x >> 6;
    const int lane = threadIdx.x & 63;
    const int gw   = blockIdx.x * 4 + wid;   // 0..GWAVES-1
    const int quad = lane >> 4;
    const int col  = lane & 15;
    const int half = quad & 1;
    const int lhalf = quad >> 1;

    // constants, L2-hot (8 KB shared by all waves)
    bf16x8 wf[8];
#pragma unroll
    for (int kb = 0; kb < 8; ++kb)
        wf[kb] = *(const bf16x8*)(wfrag + (kb * 64 + lane) * 8);
    const bf16x8 bq0 = *(const bf16x8*)(bond_bf + 0 * 16 + half * 8);
    const bf16x8 bq1 = *(const bf16x8*)(bond_bf + 1 * 16 + half * 8);
    const bf16x8 bq2 = *(const bf16x8*)(bond_bf + 2 * 16 + half * 8);
    const bf16x8 bq3 = *(const bf16x8*)(bond_bf + 3 * 16 + half * 8);
    const float bias_c = bias[col];

    Early earA, earB;
    Late  latA, latB;
    Gath  gA, gB;

    int tn = gw + GWAVES;      // tile whose gathers are issued next
    int tf = tn + GWAVES;      // tile whose streams are loaded next

    // prologue: fill the pipeline
    load_early(earA, gw, col, lhalf, quad, n_col, p_row);
    load_late (latA, gw, col, lhalf, quad, n_val, e_val, be2, p_val);
    if (tn < NTILES) load_early(earB, tn, col, lhalf, quad, n_col, p_row);
    issue_gathers(gA, earA, nfeat_bf, fd, half, col);
    if (tn < NTILES) load_late(latB, tn, col, lhalf, quad, n_val, e_val, be2, p_val);

    for (;;) {
        STEP(A, B);
        STEP(B, A);
    }
tail_done: ;
}

// fallback only (workspace too small for fd table)
__global__ __launch_bounds__(256) void gate_kernel(
    const float* __restrict__ degs,  // [N]
    const float* __restrict__ W0,    // [1,32]
    const float* __restrict__ b0,    // [32]
    const float* __restrict__ W1,    // [32,16]
    const float* __restrict__ b1,    // [16]
    float* __restrict__ out)         // [N,16] in-place multiply
{
    int n = blockIdx.x * 256 + threadIdx.x;
    if (n >= NN) return;
    float dg = degs[n];
    float4 a0 = ((const float4*)b1)[0];
    float4 a1 = ((const float4*)b1)[1];
    float4 a2 = ((const float4*)b1)[2];
    float4 a3 = ((const float4*)b1)[3];
#pragma unroll
    for (int j = 0; j < 32; ++j) {
        float h = fmaxf(fmaf(dg, W0[j], b0[j]), 0.f);
        const float4* w1r = (const float4*)(W1 + j * 16);
        a0 = fma4(h, w1r[0], a0);
        a1 = fma4(h, w1r[1], a1);
        a2 = fma4(h, w1r[2], a2);
        a3 = fma4(h, w1r[3], a3);
    }
    float4* o = (float4*)(out + (size_t)n * DD);
    float4 v0 = o[0], v1 = o[1], v2 = o[2], v3 = o[3];
    v0.x *= a0.x; v0.y *= a0.y; v0.z *= a0.z; v0.w *= a0.w;
    v1.x *= a1.x; v1.y *= a1.y; v1.z *= a1.z; v1.w *= a1.w;
    v2.x *= a2.x; v2.y *= a2.y; v2.z *= a2.z; v2.w *= a2.w;
    v3.x *= a3.x; v3.y *= a3.y; v3.z *= a3.z; v3.w *= a3.w;
    o[0] = v0; o[1] = v1; o[2] = v2; o[3] = v3;
}

extern "C" void kernel_launch(void* const* d_in, const int* in_sizes, int n_in,
                              void* d_out, int out_size, void* d_ws, size_t ws_size,
                              hipStream_t stream) {
    const float* nfeat     = (const float*)d_in[0];
    const int*   efeat_idx = (const int*)d_in[1];
    // d_in[2] n_row = arange(M), unused
    const int*   n_col     = (const int*)d_in[3];
    const float* n_val     = (const float*)d_in[4];
    // d_in[5] e_row = arange(M), unused
    const int*   e_col     = (const int*)d_in[6];
    const float* e_val     = (const float*)d_in[7];
    const int*   p_row     = (const int*)d_in[8];
    // d_in[9] p_col = arange(P), unused
    const float* p_val     = (const float*)d_in[10];
    const float* degs      = (const float*)d_in[11];
    const float* weights   = (const float*)d_in[12];
    const float* bias      = (const float*)d_in[13];
    const float* W0        = (const float*)d_in[14];
    const float* b0        = (const float*)d_in[15];
    const float* W1        = (const float*)d_in[16];
    const float* b1        = (const float*)d_in[17];
    const float* bond_emb  = (const float*)d_in[18];

    float* out = (float*)d_out;

    // ws layout (16B-aligned blocks):
    //   wfrag 8KB | nfeat_bf 3.2MB | bond 128B | be2 1MB | ei2 100KB | fd 6.4MB
    char* wsb = (char*)d_ws;
    __bf16*        wfrag    = (__bf16*)wsb;                                 // 8,192 B
    __bf16*        nfeat_bf = (__bf16*)(wsb + 8192);                        // 3,200,000 B
    __bf16*        bond_bf  = (__bf16*)(wsb + 8192 + 3200000);              // 128 B
    unsigned char* be2      = (unsigned char*)(wsb + 8192 + 3200000 + 128); // 1,000,000 B
    const size_t   ei2_off  = 8192 + 3200000 + 128 + 1000000;               // 4,208,320
    const size_t   fd_off   = ei2_off + (NE / 4);                           // +100,000
    const bool     use_lds_be2 = ws_size >= fd_off;
    const bool     fuse_gate   = ws_size >= fd_off + (size_t)NN * DD * 4;
    unsigned int*  ei2 = use_lds_be2 ? (unsigned int*)(wsb + ei2_off) : nullptr;
    float*         fd  = fuse_gate   ? (float*)(wsb + fd_off)         : nullptr;

    // grid covers max(NN*DD, MM/4 fallback) = 1.6M threads
    init_kernel<<<(NN * DD + 255) / 256, 256, 0, stream>>>(
        weights, nfeat, bond_emb, e_col, efeat_idx,
        degs, W0, b0, W1, b1,
        wfrag, nfeat_bf, bond_bf, be2, ei2, fd, out);

    if (use_lds_be2)
        be2_kernel<<<250, 256, 0, stream>>>(e_col, ei2, be2);

    // 2048 waves, depth-3 pipeline (exact round-2 structure, best measured)
    perm_kernel<<<PERM_BLOCKS, 256, 0, stream>>>(
        nfeat_bf, n_col, n_val, e_val, be2, p_row, p_val,
        wfrag, bias, bond_bf, fd, out);

    if (!fuse_gate)
        gate_kernel<<<(NN + 255) / 256, 256, 0, stream>>>(degs, W0, b0, W1, b1, out);
}